// Round 7
// baseline (386.801 us; speedup 1.0000x reference)
//
#include <hip/hip_runtime.h>

#define Bn 512
#define Tn 512
#define Cn 64
#define NCH 16             // chains per wave
#define NGRP (Bn / NCH)    // 32 wave-groups per direction
#define LDP 20             // LDS row stride (f32) for [state][chain] buffers

// R12: MFMA-batched CRF. Evidence R5-R11: every f32-VALU engine costs
// 800-1270 cy/step (6 engines tried); the vector-issue floor itself is
// ~300cy/step and stalls won't yield. Switch pipes: batch 16 chains/wave,
// per step one (16x64)@(64x64) matmul = 8 mfma_f32_16x16x32_bf16, with W
// split into bf16 hi+lo residual (16 MFMA) to kill systematic bf16 error.
// D->A relayout via small LDS transpose (amortized over 16 chains); E
// applied A-side (contiguous); per-chain renorm every 4 steps in-register.

typedef float f4    __attribute__((ext_vector_type(4)));
typedef short bfrag __attribute__((ext_vector_type(8)));   // 8 bf16
typedef unsigned int u32x4 __attribute__((ext_vector_type(4)));

static __device__ __forceinline__ unsigned int pkbf16(float a, float b) {
    unsigned int r;
    asm("v_cvt_pk_bf16_f32 %0, %1, %2" : "=v"(r) : "v"(a), "v"(b));
    return r;
}

template <int CTRL>
static __device__ __forceinline__ float fmax_dpp(const float v) {
    const int o = __builtin_amdgcn_update_dpp(__float_as_int(v), __float_as_int(v),
                                              CTRL, 0xF, 0xF, false);
    return fmaxf(v, __int_as_float(o));
}
// max across each 16-lane row (quad xor1, xor2, half-mirror, mirror)
static __device__ __forceinline__ float rowmax16(float v) {
    v = fmax_dpp<0x0B1>(v);
    v = fmax_dpp<0x04E>(v);
    v = fmax_dpp<0x141>(v);
    v = fmax_dpp<0x140>(v);
    return v;
}
static __device__ __forceinline__ f4 mfma16(bfrag a, bfrag b, f4 c) {
    return __builtin_amdgcn_mfma_f32_16x16x32_bf16(a, b, c, 0, 0, 0);
}

// blocks 0..31: forward, 16 chains each (steps t=1..256).
// blocks 32..63: backward (factors u=511..257, 255 steps).
__global__ __launch_bounds__(64)
__attribute__((amdgpu_waves_per_eu(1, 1)))
void crf_mfma_kernel(const float* __restrict__ emissions,
                     const int*   __restrict__ mask,
                     const float* __restrict__ transitions,
                     const float* __restrict__ start_t,
                     const float* __restrict__ end_t,
                     float*       __restrict__ ws_alpha,   // [Bn][Cn] alpha-hat_256 (pre-E256)
                     float*       __restrict__ ws_beta,    // [Bn][Cn] beta_256
                     float*       __restrict__ ws_lsF,     // [Bn]
                     float*       __restrict__ ws_lsB,     // [Bn]
                     float*       __restrict__ out)
{
    const int  blk = blockIdx.x;
    const bool fwd = blk < NGRP;
    const int  b0  = (fwd ? blk : blk - NGRP) * NCH;
    const int  l   = threadIdx.x;
    const int  lg  = l >> 4;     // k-group 0..3
    const int  lo4 = l & 15;     // m/n lane index

    if (blk == 0 && l == 0) out[0] = 0.f;

    __shared__ __align__(16) float lT[Cn * Cn];
    __shared__ __align__(16) float lA[2][Cn * LDP];
    __shared__ float sc[NCH];

    {   // stage transitions, coalesced
        const f4* T4  = (const f4*)transitions;
        f4*       lT4 = (f4*)lT;
#pragma unroll
        for (int q = 0; q < 16; ++q) lT4[q * 64 + l] = T4[q * 64 + l];
    }
    __builtin_amdgcn_wave_barrier();

    // B fragments of exp(T): hi bf16 + residual-lo bf16. Slot k-formula
    // kk = kh*32 + lg*8 + ii is shared by A and B packs (HW k-map cancels).
    bfrag whi[4][2], wlo[4][2];
#pragma unroll
    for (int n0 = 0; n0 < 4; ++n0)
#pragma unroll
        for (int kh = 0; kh < 2; ++kh) {
            float wv[8];
#pragma unroll
            for (int ii = 0; ii < 8; ++ii) {
                const int kk = kh * 32 + lg * 8 + ii;
                const int jj = n0 * 16 + lo4;
                wv[ii] = __expf(fwd ? lT[kk * Cn + jj] : lT[jj * Cn + kk]);
            }
            u32x4 H, L;
#pragma unroll
            for (int p = 0; p < 4; ++p) {
                const unsigned int h = pkbf16(wv[2*p], wv[2*p+1]);
                const float h0 = __uint_as_float((h & 0xffffu) << 16);
                const float h1 = __uint_as_float(h & 0xffff0000u);
                H[p] = h;
                L[p] = pkbf16(wv[2*p] - h0, wv[2*p+1] - h1);
            }
            whi[n0][kh] = __builtin_bit_cast(bfrag, H);
            wlo[n0][kh] = __builtin_bit_cast(bfrag, L);
        }

    // per-lane emission base: chain b0+lo4, state offset lg*8
    const f4* em4 = (const f4*)(emissions + (size_t)(b0 + lo4) * Tn * Cn + lg * 8);
    float ls[4];
    bfrag a0, a1;
    const f4 zz = {0.f, 0.f, 0.f, 0.f};

    if (fwd) {
        {   // A_1 = alpha_0 = exp(start + e[0] - m0), A-layout
            float v[16];
#pragma unroll
            for (int z = 0; z < 4; ++z) {
                const f4 e = em4[(z >> 1) * 8 + (z & 1)];
#pragma unroll
                for (int q = 0; q < 4; ++q)
                    v[z*4+q] = start_t[(z>>1)*32 + lg*8 + (z&1)*4 + q] + e[q];
            }
            float mx = v[0];
#pragma unroll
            for (int i2 = 1; i2 < 16; ++i2) mx = fmaxf(mx, v[i2]);
            mx = fmaxf(mx, __int_as_float(__builtin_amdgcn_ds_swizzle(__float_as_int(mx), 0x401F)));
            mx = fmaxf(mx, __shfl_xor(mx, 32, 64));
            u32x4 A0, A1;
#pragma unroll
            for (int p = 0; p < 4; ++p) {
                A0[p] = pkbf16(__expf(v[2*p]   - mx), __expf(v[2*p+1]   - mx));
                A1[p] = pkbf16(__expf(v[8+2*p] - mx), __expf(v[8+2*p+1] - mx));
            }
            a0 = __builtin_bit_cast(bfrag, A0);
            a1 = __builtin_bit_cast(bfrag, A1);
            if (l < NCH) sc[l] = mx;
        }
        __builtin_amdgcn_wave_barrier();
#pragma unroll
        for (int r = 0; r < 4; ++r) ls[r] = sc[4*lg + r];

        f4  eq0[4], eq1[4];
        int mv0, mv1;
#pragma unroll
        for (int z = 0; z < 4; ++z) {
            eq1[z] = em4[1*16 + (z>>1)*8 + (z&1)];
            eq0[z] = em4[2*16 + (z>>1)*8 + (z&1)];
        }
        mv1 = 1; if (l < NCH) mv1 = mask[(b0 + l) * Tn + 1];
        mv0 = 1; if (l < NCH) mv0 = mask[(b0 + l) * Tn + 2];

        unsigned long long mwlast = ~0ull;

#pragma unroll 1
        for (int t = 1; t <= 256; ++t) {
            const int par = t & 1;
            const f4 pfa = em4[(t+2)*16 + 0];
            const f4 pfb = em4[(t+2)*16 + 1];
            const f4 pfc = em4[(t+2)*16 + 8];
            const f4 pfd = em4[(t+2)*16 + 9];
            int pfm = 1; if (l < NCH) pfm = mask[(b0 + l) * Tn + (t + 2)];

            f4 acc0 = mfma16(a0, whi[0][0], zz);
            f4 acc1 = mfma16(a0, whi[1][0], zz);
            f4 acc2 = mfma16(a0, whi[2][0], zz);
            f4 acc3 = mfma16(a0, whi[3][0], zz);
            acc0 = mfma16(a1, whi[0][1], acc0);
            acc1 = mfma16(a1, whi[1][1], acc1);
            acc2 = mfma16(a1, whi[2][1], acc2);
            acc3 = mfma16(a1, whi[3][1], acc3);
            acc0 = mfma16(a0, wlo[0][0], acc0);
            acc1 = mfma16(a0, wlo[1][0], acc1);
            acc2 = mfma16(a0, wlo[2][0], acc2);
            acc3 = mfma16(a0, wlo[3][0], acc3);
            acc0 = mfma16(a1, wlo[0][1], acc0);
            acc1 = mfma16(a1, wlo[1][1], acc1);
            acc2 = mfma16(a1, wlo[2][1], acc2);
            acc3 = mfma16(a1, wlo[3][1], acc3);

            const unsigned long long mw = __ballot((par ? mv1 : mv0) != 0);
            const bool all1 = (mw == ~0ull);
            mwlast = mw;

            if ((t & 3) == 0) {     // per-chain renorm, in-register
#pragma unroll
                for (int r = 0; r < 4; ++r) {
                    float mr = fmaxf(fmaxf(acc0[r], acc1[r]), fmaxf(acc2[r], acc3[r]));
                    mr = rowmax16(mr);
                    float scl = __builtin_amdgcn_rcpf(mr);
                    float lga = __logf(mr);
                    if (!all1) {
                        const bool fz = !((mw >> (4*lg + r)) & 1);
                        scl = fz ? 1.0f : scl;
                        lga = fz ? 0.0f : lga;
                    }
                    ls[r] += lga;
                    acc0[r] *= scl; acc1[r] *= scl; acc2[r] *= scl; acc3[r] *= scl;
                }
            }

            // publish alpha-hat_t (pre-E) in [state][chain] layout
            *(f4*)&lA[par][(     lo4) * LDP + 4*lg] = acc0;
            *(f4*)&lA[par][(16 + lo4) * LDP + 4*lg] = acc1;
            *(f4*)&lA[par][(32 + lo4) * LDP + 4*lg] = acc2;
            *(f4*)&lA[par][(48 + lo4) * LDP + 4*lg] = acc3;
            __builtin_amdgcn_wave_barrier();

            if (t != 256) {
                float ex[16];
#pragma unroll
                for (int z = 0; z < 4; ++z) {
                    const f4 e = par ? eq1[z] : eq0[z];
#pragma unroll
                    for (int q = 0; q < 4; ++q) ex[z*4+q] = __expf(e[q]);
                }
                u32x4 NA0, NA1;
#pragma unroll
                for (int p = 0; p < 4; ++p) {
                    const float f0 = lA[par][(     lg*8 + 2*p    ) * LDP + lo4] * ex[2*p];
                    const float f1 = lA[par][(     lg*8 + 2*p + 1) * LDP + lo4] * ex[2*p+1];
                    const float f2 = lA[par][(32 + lg*8 + 2*p    ) * LDP + lo4] * ex[8+2*p];
                    const float f3 = lA[par][(32 + lg*8 + 2*p + 1) * LDP + lo4] * ex[8+2*p+1];
                    NA0[p] = pkbf16(f0, f1);
                    NA1[p] = pkbf16(f2, f3);
                }
                if (!all1) {        // frozen chains carry previous A
                    const bool fz = !((mw >> lo4) & 1);
                    const u32x4 O0 = __builtin_bit_cast(u32x4, a0);
                    const u32x4 O1 = __builtin_bit_cast(u32x4, a1);
#pragma unroll
                    for (int p = 0; p < 4; ++p) {
                        NA0[p] = fz ? O0[p] : NA0[p];
                        NA1[p] = fz ? O1[p] : NA1[p];
                    }
                }
                a0 = __builtin_bit_cast(bfrag, NA0);
                a1 = __builtin_bit_cast(bfrag, NA1);
                if (par) { eq1[0]=pfa; eq1[1]=pfb; eq1[2]=pfc; eq1[3]=pfd; mv1 = pfm; }
                else     { eq0[0]=pfa; eq0[1]=pfb; eq0[2]=pfc; eq0[3]=pfd; mv0 = pfm; }
            }
        }

        __builtin_amdgcn_wave_barrier();
#pragma unroll
        for (int s = 0; s < 16; ++s) {
            const int i2 = (s >> 3) * 32 + lg * 8 + (s & 7);
            ws_alpha[(size_t)(b0 + lo4) * Cn + i2] = lA[0][i2 * LDP + lo4];
        }
        if (mwlast != ~0ull) {      // frozen at t=256: store alpha_255 * exp(-e256)
            asm volatile("s_waitcnt vmcnt(0)" ::: "memory");
            const bool fz = !((mwlast >> lo4) & 1);
            if (fz) {
                const u32x4 U0 = __builtin_bit_cast(u32x4, a0);
                const u32x4 U1 = __builtin_bit_cast(u32x4, a1);
#pragma unroll
                for (int s = 0; s < 16; ++s) {
                    const int kh = s >> 3, ii = s & 7;
                    const unsigned int w = (kh == 0) ? U0[ii >> 1] : U1[ii >> 1];
                    const float av = __uint_as_float(((w >> (16 * (ii & 1))) & 0xffffu) << 16);
                    const f4 e = (s < 8) ? ((ii < 4) ? eq0[0] : eq0[1])
                                         : ((ii < 4) ? eq0[2] : eq0[3]);
                    const float ev = e[ii & 3];
                    const int i2 = kh * 32 + lg * 8 + ii;
                    ws_alpha[(size_t)(b0 + lo4) * Cn + i2] = av * __expf(0.f - ev);
                }
            }
        }
        if (lo4 == 0) {
#pragma unroll
            for (int r = 0; r < 4; ++r) ws_lsF[b0 + 4*lg + r] = ls[r];
        }
    } else {
        {   // A_0 = gamma_511 = exp(end + e[511] - m0); publish beta_511 to lA[1]
            float v[16], bv[16];
#pragma unroll
            for (int z = 0; z < 4; ++z) {
                const f4 e = em4[511*16 + (z>>1)*8 + (z&1)];
#pragma unroll
                for (int q = 0; q < 4; ++q) {
                    const int i2 = (z>>1)*32 + lg*8 + (z&1)*4 + q;
                    bv[z*4+q] = end_t[i2];
                    v[z*4+q]  = bv[z*4+q] + e[q];
                }
            }
            float mx = v[0];
#pragma unroll
            for (int i2 = 1; i2 < 16; ++i2) mx = fmaxf(mx, v[i2]);
            mx = fmaxf(mx, __int_as_float(__builtin_amdgcn_ds_swizzle(__float_as_int(mx), 0x401F)));
            mx = fmaxf(mx, __shfl_xor(mx, 32, 64));
            u32x4 A0, A1;
#pragma unroll
            for (int p = 0; p < 4; ++p) {
                A0[p] = pkbf16(__expf(v[2*p]   - mx), __expf(v[2*p+1]   - mx));
                A1[p] = pkbf16(__expf(v[8+2*p] - mx), __expf(v[8+2*p+1] - mx));
            }
            a0 = __builtin_bit_cast(bfrag, A0);
            a1 = __builtin_bit_cast(bfrag, A1);
            if (l < NCH) sc[l] = mx;
#pragma unroll
            for (int s = 0; s < 16; ++s) {
                const int i2 = (s >> 3) * 32 + lg * 8 + (s & 7);
                lA[1][i2 * LDP + lo4] = __expf(bv[s] - mx);
            }
        }
        __builtin_amdgcn_wave_barrier();
#pragma unroll
        for (int r = 0; r < 4; ++r) ls[r] = sc[4*lg + r];

        f4  eq0[4], eq1[4];
        int mv0, mv1;
#pragma unroll
        for (int z = 0; z < 4; ++z) {
            eq0[z] = em4[510*16 + (z>>1)*8 + (z&1)];
            eq1[z] = em4[509*16 + (z>>1)*8 + (z&1)];
        }
        mv0 = 1; if (l < NCH) mv0 = mask[(b0 + l) * Tn + 511];
        mv1 = 1; if (l < NCH) mv1 = mask[(b0 + l) * Tn + 510];

#pragma unroll 1
        for (int s = 0; s < 255; ++s) {     // factor u = 511 - s
            const int par = s & 1;
            const f4 pfa = em4[(508 - s)*16 + 0];
            const f4 pfb = em4[(508 - s)*16 + 1];
            const f4 pfc = em4[(508 - s)*16 + 8];
            const f4 pfd = em4[(508 - s)*16 + 9];
            int pfm = 1; if (l < NCH) pfm = mask[(b0 + l) * Tn + (509 - s)];

            f4 acc0 = mfma16(a0, whi[0][0], zz);
            f4 acc1 = mfma16(a0, whi[1][0], zz);
            f4 acc2 = mfma16(a0, whi[2][0], zz);
            f4 acc3 = mfma16(a0, whi[3][0], zz);
            acc0 = mfma16(a1, whi[0][1], acc0);
            acc1 = mfma16(a1, whi[1][1], acc1);
            acc2 = mfma16(a1, whi[2][1], acc2);
            acc3 = mfma16(a1, whi[3][1], acc3);
            acc0 = mfma16(a0, wlo[0][0], acc0);
            acc1 = mfma16(a0, wlo[1][0], acc1);
            acc2 = mfma16(a0, wlo[2][0], acc2);
            acc3 = mfma16(a0, wlo[3][0], acc3);
            acc0 = mfma16(a1, wlo[0][1], acc0);
            acc1 = mfma16(a1, wlo[1][1], acc1);
            acc2 = mfma16(a1, wlo[2][1], acc2);
            acc3 = mfma16(a1, wlo[3][1], acc3);

            const unsigned long long mw = __ballot((par ? mv1 : mv0) != 0);
            const bool all1 = (mw == ~0ull);

            if ((s & 3) == 3) {
#pragma unroll
                for (int r = 0; r < 4; ++r) {
                    float mr = fmaxf(fmaxf(acc0[r], acc1[r]), fmaxf(acc2[r], acc3[r]));
                    mr = rowmax16(mr);
                    float scl = __builtin_amdgcn_rcpf(mr);
                    float lga = __logf(mr);
                    if (!all1) {
                        const bool fz = !((mw >> (4*lg + r)) & 1);
                        scl = fz ? 1.0f : scl;
                        lga = fz ? 0.0f : lga;
                    }
                    ls[r] += lga;
                    acc0[r] *= scl; acc1[r] *= scl; acc2[r] *= scl; acc3[r] *= scl;
                }
            }

            if (!all1) {    // frozen chains keep previous beta (from other buffer)
                const f4 pv0 = *(const f4*)&lA[par ^ 1][(     lo4) * LDP + 4*lg];
                const f4 pv1 = *(const f4*)&lA[par ^ 1][(16 + lo4) * LDP + 4*lg];
                const f4 pv2 = *(const f4*)&lA[par ^ 1][(32 + lo4) * LDP + 4*lg];
                const f4 pv3 = *(const f4*)&lA[par ^ 1][(48 + lo4) * LDP + 4*lg];
#pragma unroll
                for (int r = 0; r < 4; ++r) {
                    const bool fz = !((mw >> (4*lg + r)) & 1);
                    acc0[r] = fz ? pv0[r] : acc0[r];
                    acc1[r] = fz ? pv1[r] : acc1[r];
                    acc2[r] = fz ? pv2[r] : acc2[r];
                    acc3[r] = fz ? pv3[r] : acc3[r];
                }
            }
            *(f4*)&lA[par][(     lo4) * LDP + 4*lg] = acc0;
            *(f4*)&lA[par][(16 + lo4) * LDP + 4*lg] = acc1;
            *(f4*)&lA[par][(32 + lo4) * LDP + 4*lg] = acc2;
            *(f4*)&lA[par][(48 + lo4) * LDP + 4*lg] = acc3;
            __builtin_amdgcn_wave_barrier();

            if (s != 254) {
                float ex[16];
#pragma unroll
                for (int z = 0; z < 4; ++z) {
                    const f4 e = par ? eq1[z] : eq0[z];
#pragma unroll
                    for (int q = 0; q < 4; ++q) ex[z*4+q] = __expf(e[q]);
                }
                u32x4 NA0, NA1;
#pragma unroll
                for (int p = 0; p < 4; ++p) {
                    const float f0 = lA[par][(     lg*8 + 2*p    ) * LDP + lo4] * ex[2*p];
                    const float f1 = lA[par][(     lg*8 + 2*p + 1) * LDP + lo4] * ex[2*p+1];
                    const float f2 = lA[par][(32 + lg*8 + 2*p    ) * LDP + lo4] * ex[8+2*p];
                    const float f3 = lA[par][(32 + lg*8 + 2*p + 1) * LDP + lo4] * ex[8+2*p+1];
                    NA0[p] = pkbf16(f0, f1);
                    NA1[p] = pkbf16(f2, f3);
                }
                a0 = __builtin_bit_cast(bfrag, NA0);
                a1 = __builtin_bit_cast(bfrag, NA1);
                if (par) { eq1[0]=pfa; eq1[1]=pfb; eq1[2]=pfc; eq1[3]=pfd; mv1 = pfm; }
                else     { eq0[0]=pfa; eq0[1]=pfb; eq0[2]=pfc; eq0[3]=pfd; mv0 = pfm; }
            }
        }

        __builtin_amdgcn_wave_barrier();
#pragma unroll
        for (int s = 0; s < 16; ++s) {
            const int i2 = (s >> 3) * 32 + lg * 8 + (s & 7);
            ws_beta[(size_t)(b0 + lo4) * Cn + i2] = lA[0][i2 * LDP + lo4];
        }
        if (lo4 == 0) {
#pragma unroll
            for (int r = 0; r < 4; ++r) ws_lsB[b0 + 4*lg + r] = ls[r];
        }
    }
}

// Per chain: numerator (R5-validated path) + denom = lsF+lsB+log(sum_j
// alpha_hat_256[j]*exp(e256[j])*beta_256[j]); one atomic per chain.
__global__ __launch_bounds__(64) void crf_combine_kernel(
    const float* __restrict__ emissions,
    const int*   __restrict__ tags,
    const int*   __restrict__ mask,
    const float* __restrict__ transitions,
    const float* __restrict__ start_t,
    const float* __restrict__ end_t,
    const float* __restrict__ ws_alpha,
    const float* __restrict__ ws_beta,
    const float* __restrict__ ws_lsF,
    const float* __restrict__ ws_lsB,
    float*       __restrict__ out)
{
    const int bt = blockIdx.x;
    const int j  = threadIdx.x;
    const float* em0 = emissions + (size_t)bt * Tn * Cn;
    const int*   tg  = tags + bt * Tn;
    const int*   mk  = mask + bt * Tn;

    float nsum = 0.f;
    int   mcnt = 0;
    for (int t = j; t < Tn; t += 64) {
        const int tag_t = tg[t];
        const int m_t   = mk[t];
        mcnt += m_t;
        if (t >= 1 && m_t)
            nsum += transitions[tg[t-1] * Cn + tag_t] + em0[t * Cn + tag_t];
    }
#pragma unroll
    for (int off = 32; off > 0; off >>= 1) {
        nsum += __shfl_xor(nsum, off, 64);
        mcnt += __shfl_xor(mcnt, off, 64);
    }

    float v = ws_alpha[bt * Cn + j] * __expf(em0[256 * Cn + j]) * ws_beta[bt * Cn + j];
#pragma unroll
    for (int off = 32; off > 0; off >>= 1) v += __shfl_xor(v, off, 64);

    if (j == 0) {
        const float num   = start_t[tg[0]] + em0[tg[0]] + nsum + end_t[tg[mcnt - 1]];
        const float denom = ws_lsF[bt] + ws_lsB[bt] + __logf(v);
        atomicAdd(out, (denom - num) * (1.0f / Bn));
    }
}

extern "C" void kernel_launch(void* const* d_in, const int* in_sizes, int n_in,
                              void* d_out, int out_size, void* d_ws, size_t ws_size,
                              hipStream_t stream)
{
    const float* emissions   = (const float*)d_in[0];
    const int*   tags        = (const int*)d_in[1];
    const int*   mask        = (const int*)d_in[2];
    const float* transitions = (const float*)d_in[3];
    const float* start_t     = (const float*)d_in[4];
    const float* end_t       = (const float*)d_in[5];

    float* ws       = (float*)d_ws;
    float* ws_alpha = ws;                       // 512*64
    float* ws_beta  = ws_alpha + Bn * Cn;       // 512*64
    float* ws_lsF   = ws_beta + Bn * Cn;        // 512
    float* ws_lsB   = ws_lsF + Bn;              // 512

    crf_mfma_kernel<<<2 * NGRP, 64, 0, stream>>>(emissions, mask, transitions,
                                                 start_t, end_t,
                                                 ws_alpha, ws_beta, ws_lsF, ws_lsB,
                                                 (float*)d_out);
    crf_combine_kernel<<<Bn, 64, 0, stream>>>(emissions, tags, mask, transitions,
                                              start_t, end_t,
                                              ws_alpha, ws_beta, ws_lsF, ws_lsB,
                                              (float*)d_out);
}